// Round 13
// baseline (123.036 us; speedup 1.0000x reference)
//
#include <hip/hip_runtime.h>

#define EPSF  (1e-7f)
#define LN2F  (0.69314718055994530942f)
#define LOG2(x) __builtin_amdgcn_logf(x)

// Fenced waitcnts: exact instruction + compiler memory fence.
__device__ __forceinline__ void waitcnt_vm8()   { asm volatile("s_waitcnt vmcnt(8)"   ::: "memory"); }
__device__ __forceinline__ void waitcnt_lgkm0() { asm volatile("s_waitcnt lgkmcnt(0)" ::: "memory"); }

template<int CTRL>
__device__ __forceinline__ int dpp_i(int x) {
    return __builtin_amdgcn_update_dpp(x, x, CTRL, 0xF, 0xF, true);
}
// Full-wave shift-up-by-1 (lane i <- lane i-1). Rows 1-3 proven exact
// (R6-R9, absmax 0.0). ROW 0's result must NEVER be consumed unmasked:
// row_bcast15 row-0 semantics are unverified (R10-R12 failures traced here).
__device__ __forceinline__ float shift_up1_f(float x, bool rowhead) {
    int xi = __float_as_int(x);
    int sh = dpp_i<0x111>(xi);
    int bc = dpp_i<0x142>(xi);
    return __int_as_float(rowhead ? bc : sh);
}
__device__ __forceinline__ int shift_up1_i(int x, bool rowhead) {
    int sh = dpp_i<0x111>(x);
    int bc = dpp_i<0x142>(x);
    return rowhead ? bc : sh;
}
// Raw barrier without the compiler's vmcnt(0) drain; producer guarantees
// residency with fenced fine-grained waitcnts (R8/R9-proven).
__device__ __forceinline__ void wg_barrier() {
    asm volatile("" ::: "memory");
    __builtin_amdgcn_s_barrier();
    asm volatile("" ::: "memory");
}

// 2 waves per block, one block per batch element. T=512, C=128, L=64, Tin==T.
// Linear-domain forward CTC with 2-STEP COMPOSED updates:
//   alpha_{t+2} = (A_{t+1} A_t) alpha_t, bandwidth 4 states = 2 lanes.
// Producer (wave 1): DMA 16-row phases into 2-slot raw ring (vmcnt(8) pacing)
//   and builds per-pair composed coefficients (functions of y only).
//   Lane-0 exposure fix: co2 is forcibly zeroed at lane 0 (its multiplicand
//   ao_{i-1} is ao_{-1}=0; zeroing makes the unverified row-0 DPP value
//   harmless under either read-0 or read-self semantics).
// Consumer (wave 0): 256 composed steps; 4 DPP shifts + 2 scale conversions
//   + 2 FMA dots per step; per-lane power-of-2 renorm every 2 composed steps
//   (= 4 t, proven window). Pre-state (a0=1, ao=ae=0) -> first composed step
//   yields alpha_1 exactly (verified algebra).
__global__ __launch_bounds__(128, 1)
void ctc_fwd_kernel(const float* __restrict__ y_pred,
                    const int*   __restrict__ labels,
                    const int*   __restrict__ input_length,
                    const int*   __restrict__ label_length,
                    float*       __restrict__ out)
{
    const int b    = blockIdx.x;
    const int wave = threadIdx.x >> 6;
    const int lane = threadIdx.x & 63;
    const int ll   = label_length[b];
    (void)input_length;                        // == 512 by construction

    __shared__ float  raw[2][16][128];         // 16 KB raw ring
    __shared__ float4 cmp4[2][8][64];          // 16 KB: co0..co3 per pair
    __shared__ float2 cmp2[2][8][64];          //  8 KB: ce1,ce2 per pair
    __shared__ float  cba[2][8];               // cb per pair (uniform)

    const float* g0 = y_pred + (size_t)b * 512 * 128;
    const int*   lb = labels + (size_t)b * 64;

    const int  l       = lb[lane];             // 0..C-2, never blank
    const int  lprev   = __shfl_up(l, 1);      // one-time DS op
    const bool k       = (lane >= 1) && (l != lprev);   // skip into s=2i+1
    const bool rowhead = ((lane & 15) == 0);

    if (wave == 1) {
        // ---------------- producer ----------------
        auto dma = [&](int ph) {
            int slot = ph & 1, phc = ph < 31 ? ph : 31;   // tail: dummy reload
            const float* g = g0 + (size_t)phc * 16 * 128;
            float* lp = &raw[slot][0][0];
            #pragma unroll
            for (int c = 0; c < 8; ++c)
                __builtin_amdgcn_global_load_lds(
                    (const __attribute__((address_space(1))) void*)(g + c * 256 + lane * 4),
                    (__attribute__((address_space(3))) void*)(lp + c * 256),
                    16, 0, 0);                 // 16B/lane x 64 = 1KB
        };
        auto coef = [&](int ph) {              // raw[slot] -> composed coeffs
            int slot = ph & 1, par = ph & 1;
            #pragma unroll
            for (int m = 0; m < 8; ++m) {      // pair (t1,t2)=(2m,2m+1) of phase
                float yl1 = raw[slot][2 * m][l]       + EPSF;
                float yl2 = raw[slot][2 * m + 1][l]   + EPSF;
                float yb1 = raw[slot][2 * m][127]     + EPSF;  // uniform
                float yb2 = raw[slot][2 * m + 1][127] + EPSF;
                float p1  = shift_up1_f(yl1, rowhead);  // lane i-1's yl1
                float t1  = yl1 + yb1;
                float co0 = yl2 * yl1;                  // * ao_i
                float co1 = yl2 * t1;                   // * ae_{i-1} (lane0: a0)
                float tk  = k ? (yl1 + p1) : 0.f;
                float co2 = (lane == 0) ? 0.f           // mask: ao_{-1}=0; row-0
                          : yl2 * (yb1 + tk);           //   DPP value unverified
                float co3 = k ? yl2 * p1 : 0.f;         // * ae_{i-2} (lane1: a0)
                float ce1 = yb2 * t1;                   // * ao_i
                float ce2 = yb2 * yl1;                  // * ae_{i-1} (lane0: a0)
                cmp4[par][m][lane] = make_float4(co0, co1, co2, co3);
                cmp2[par][m][lane] = make_float2(ce1, ce2);
                if (lane == 0) cba[par][m] = yb1 * yb2; // * ae_i / a0 decay
            }
        };
        dma(0); dma(1);
        waitcnt_vm8();                         // raw0 resident
        coef(0);
        waitcnt_lgkm0();
        wg_barrier();                          // #1: cmp0 ready
        for (int p = 0; p < 32; ++p) {
            dma(p + 2);
            waitcnt_vm8();                     // raw[p+1] resident
            coef(p + 1);                       // tail ph=32: dummy, unused
            waitcnt_lgkm0();
            wg_barrier();                      // cmp[p+1] ready
        }
    } else {
        // ---------------- consumer ----------------
        const float kp0   = k ? 1.f : 0.f;     // own skip
        const float kp1   = __shfl_up(kp0, 1); // prev lane's skip (lane0: 0)
        const bool  lane0 = (lane == 0);
        const bool  lane1 = (lane == 1);
        float a0 = 1.f, ao = 0.f, ae = 0.f;    // pre-state: step -> alpha_1
        int   esum = 0;
        float fsc1 = 1.f, fsc2 = 1.f;          // 2^(esum_{i-1}-esum_i), i-2

        wg_barrier();                          // cmp0 ready
        for (int p = 0; p < 32; ++p) {
            const int par = p & 1;
            float4 C4[8]; float2 C2[8]; float CB[8];
            #pragma unroll
            for (int m = 0; m < 8; ++m) {
                C4[m] = cmp4[par][m][lane];
                C2[m] = cmp2[par][m][lane];
                CB[m] = cba[par][m];
            }
            #pragma unroll
            for (int m = 0; m < 8; ++m) {
                float s1o = shift_up1_f(ao, rowhead);   // ao_{i-1} (raw)
                float s1e = shift_up1_f(ae, rowhead);   // ae_{i-1}
                float s2o = shift_up1_f(s1o, rowhead);  // ao_{i-2}
                float s2e = shift_up1_f(s1e, rowhead);  // ae_{i-2}
                s1o *= fsc1; s1e *= fsc1;
                s2o *= fsc2; s2e *= fsc2;
                s1e = lane0 ? a0 : s1e;        // state-0 inflow (verified)
                s2e = lane1 ? a0 : s2e;        // lane0's s2e: co3=0 anyway
                float nao = C4[m].x * ao + C4[m].y * s1e + C4[m].z * s1o
                          + C4[m].w * s2e + (C4[m].w * kp1) * s2o;
                float nae = CB[m] * ae + C2[m].x * ao + C2[m].y * s1e
                          + (C2[m].y * kp0) * s1o;
                a0 *= CB[m];
                ao = nao; ae = nae;
                if (m & 1) {                   // renorm every 2 pairs = 4 t
                    float lm    = fmaxf(ae, ao);
                    float basis = (lm > 0.f) ? lm : a0;   // a0-anchor if dead
                    int   e  = (__float_as_int(basis) >> 23) & 0xFF;
                    float sc = __int_as_float((254 - e) << 23);   // 2^(127-e)
                    ae *= sc; ao *= sc; a0 *= sc;
                    esum += e - 127;
                    int en1 = shift_up1_i(esum, rowhead);
                    int de1 = en1 - esum;
                    de1 = de1 < -127 ? -127 : (de1 > 127 ? 127 : de1);
                    fsc1 = __int_as_float((127 + de1) << 23);
                    int en2 = shift_up1_i(en1, rowhead);
                    int de2 = en2 - esum;
                    de2 = de2 < -127 ? -127 : (de2 > 127 ? 127 : de2);
                    fsc2 = __int_as_float((127 + de2) << 23);
                }
            }
            wg_barrier();                      // next phase's cmp ready
        }

        // s_end = 2*ll -> lane (ll-1).ae ; s_end-1 -> lane (ll-1).ao ; ll >= 16
        if (lane == ll - 1) {
            out[b] = -(LOG2(ae + ao) + (float)esum) * LN2F;
        }
    }
}

extern "C" void kernel_launch(void* const* d_in, const int* in_sizes, int n_in,
                              void* d_out, int out_size, void* d_ws, size_t ws_size,
                              hipStream_t stream) {
    const float* y_pred       = (const float*)d_in[0];
    const int*   labels       = (const int*)d_in[1];
    const int*   input_length = (const int*)d_in[2];
    const int*   label_length = (const int*)d_in[3];
    float*       out          = (float*)d_out;

    const int B = in_sizes[2];          // 256
    ctc_fwd_kernel<<<B, 128, 0, stream>>>(y_pred, labels, input_length,
                                          label_length, out);
}